// Round 1
// baseline (843.300 us; speedup 1.0000x reference)
//
#include <hip/hip_runtime.h>

#define N_NODES 50000
#define N_EDGES 800000
#define IN_C 128
#define MSG_C 64
#define OUT_C 128

// ---------------- scatter-add: message [E,64] += into aggr[N,64] by dest ----
__global__ __launch_bounds__(256) void scatter_add_kernel(
    const int* __restrict__ edge_index, const float* __restrict__ message,
    float* __restrict__ aggr)
{
    long tid = (long)blockIdx.x * 256 + threadIdx.x;
    if (tid >= (long)N_EDGES * 16) return;
    int e = (int)(tid >> 4);
    int g = (int)(tid & 15);
    int dest = edge_index[N_EDGES + e];   // second row of [2,E]
    float4 m = *reinterpret_cast<const float4*>(message + (long)e * MSG_C + g * 4);
    float* dst = aggr + (long)dest * MSG_C + g * 4;
    atomicAdd(dst + 0, m.x);
    atomicAdd(dst + 1, m.y);
    atomicAdd(dst + 2, m.z);
    atomicAdd(dst + 3, m.w);
}

// ---------------- fused 3-layer MLP + LayerNorm ----------------------------
// block = 256 threads, 64 nodes per block.
// per-thread: 4 rows x 8 cols register tile.
template<int STRIDE>
__device__ __forceinline__ void gemm_chunk(const float* __restrict__ A,
                                           const float* __restrict__ sWp,
                                           int rg, int cg, int kbase,
                                           float acc[4][8])
{
    #pragma unroll 4
    for (int kk = 0; kk < 64; ++kk) {
        float a[4];
        #pragma unroll
        for (int i = 0; i < 4; ++i)
            a[i] = A[(rg * 4 + i) * STRIDE + kbase + kk];   // broadcast reads
        float4 w0 = *reinterpret_cast<const float4*>(sWp + kk * 128 + cg * 8);
        float4 w1 = *reinterpret_cast<const float4*>(sWp + kk * 128 + cg * 8 + 4);
        float w[8] = {w0.x, w0.y, w0.z, w0.w, w1.x, w1.y, w1.z, w1.w};
        #pragma unroll
        for (int i = 0; i < 4; ++i)
            #pragma unroll
            for (int j = 0; j < 8; ++j)
                acc[i][j] += a[i] * w[j];
    }
}

__device__ __forceinline__ void load_w_chunk(const float* __restrict__ W, int krow0,
                                             float* __restrict__ sW, int tid)
{
    #pragma unroll
    for (int idx = tid; idx < 64 * 32; idx += 256) {
        int r = idx >> 5, c4 = idx & 31;
        *reinterpret_cast<float4*>(sW + r * 128 + c4 * 4) =
            *reinterpret_cast<const float4*>(W + (long)(krow0 + r) * 128 + c4 * 4);
    }
}

__global__ __launch_bounds__(256) void mlp_ln_kernel(
    const float* __restrict__ x, const float* __restrict__ aggr,
    const float* __restrict__ W1, const float* __restrict__ b1,
    const float* __restrict__ W2, const float* __restrict__ b2,
    const float* __restrict__ W3, const float* __restrict__ gamma,
    const float* __restrict__ beta, float* __restrict__ out)
{
    __shared__ float sA[64][196];   // h0 (192 cols), later reused for h2 (128)
    __shared__ float sB[64][132];   // h1
    __shared__ float sW[64][128];   // weight K-chunk

    const int tid = threadIdx.x;
    const int rg = tid >> 4;        // 0..15, 4 rows each
    const int cg = tid & 15;        // 0..15, 8 cols each
    const int base = blockIdx.x * 64;

    // ---- stage x -> sA[:,0:128]
    for (int idx = tid; idx < 64 * 32; idx += 256) {
        int r = idx >> 5, c4 = idx & 31;
        int gr = base + r;
        float4 v = make_float4(0.f, 0.f, 0.f, 0.f);
        if (gr < N_NODES) v = *reinterpret_cast<const float4*>(x + (long)gr * IN_C + c4 * 4);
        *reinterpret_cast<float4*>(&sA[r][c4 * 4]) = v;
    }
    // ---- stage aggr -> sA[:,128:192]
    for (int idx = tid; idx < 64 * 16; idx += 256) {
        int r = idx >> 4, c4 = idx & 15;
        int gr = base + r;
        float4 v = make_float4(0.f, 0.f, 0.f, 0.f);
        if (gr < N_NODES) v = *reinterpret_cast<const float4*>(aggr + (long)gr * MSG_C + c4 * 4);
        *reinterpret_cast<float4*>(&sA[r][IN_C + c4 * 4]) = v;
    }

    float acc[4][8];

    // ===== layer 1: h1 = leaky(h0 @ W1 + b1), K = 192
    #pragma unroll
    for (int i = 0; i < 4; ++i)
        #pragma unroll
        for (int j = 0; j < 8; ++j) acc[i][j] = 0.f;
    for (int kc = 0; kc < 3; ++kc) {
        __syncthreads();                       // sW free / sA staged
        load_w_chunk(W1, kc * 64, &sW[0][0], tid);
        __syncthreads();
        gemm_chunk<196>(&sA[0][0], &sW[0][0], rg, cg, kc * 64, acc);
    }
    #pragma unroll
    for (int i = 0; i < 4; ++i)
        #pragma unroll
        for (int j = 0; j < 8; ++j) {
            float v = acc[i][j] + b1[cg * 8 + j];
            v = v > 0.f ? v : 0.2f * v;
            sB[rg * 4 + i][cg * 8 + j] = v;
        }

    // ===== layer 2: h2 = leaky(h1 @ W2 + b2), K = 128
    #pragma unroll
    for (int i = 0; i < 4; ++i)
        #pragma unroll
        for (int j = 0; j < 8; ++j) acc[i][j] = 0.f;
    for (int kc = 0; kc < 2; ++kc) {
        __syncthreads();                       // also orders sB writes -> reads
        load_w_chunk(W2, kc * 64, &sW[0][0], tid);
        __syncthreads();
        gemm_chunk<132>(&sB[0][0], &sW[0][0], rg, cg, kc * 64, acc);
    }
    #pragma unroll
    for (int i = 0; i < 4; ++i)
        #pragma unroll
        for (int j = 0; j < 8; ++j) {
            float v = acc[i][j] + b2[cg * 8 + j];
            v = v > 0.f ? v : 0.2f * v;
            sA[rg * 4 + i][cg * 8 + j] = v;    // h2 reuses sA
        }

    // ===== layer 3: h3 = h2 @ W3 (no bias), K = 128
    #pragma unroll
    for (int i = 0; i < 4; ++i)
        #pragma unroll
        for (int j = 0; j < 8; ++j) acc[i][j] = 0.f;
    for (int kc = 0; kc < 2; ++kc) {
        __syncthreads();                       // orders h2 writes -> reads
        load_w_chunk(W3, kc * 64, &sW[0][0], tid);
        __syncthreads();
        gemm_chunk<196>(&sA[0][0], &sW[0][0], rg, cg, kc * 64, acc);
    }

    // ===== LayerNorm epilogue (row owned by 16 lanes: cg groups)
    float g8[8], be8[8];
    #pragma unroll
    for (int j = 0; j < 8; ++j) { g8[j] = gamma[cg * 8 + j]; be8[j] = beta[cg * 8 + j]; }

    #pragma unroll
    for (int i = 0; i < 4; ++i) {
        float s1 = 0.f, s2 = 0.f;
        #pragma unroll
        for (int j = 0; j < 8; ++j) { s1 += acc[i][j]; s2 += acc[i][j] * acc[i][j]; }
        #pragma unroll
        for (int m = 8; m >= 1; m >>= 1) {
            s1 += __shfl_xor(s1, m);
            s2 += __shfl_xor(s2, m);
        }
        float mu = s1 * (1.f / 128.f);
        float var = s2 * (1.f / 128.f) - mu * mu;
        float rs = rsqrtf(var + 1e-5f);
        int gr = base + rg * 4 + i;
        if (gr < N_NODES) {
            float4 o0, o1;
            o0.x = (acc[i][0] - mu) * rs * g8[0] + be8[0];
            o0.y = (acc[i][1] - mu) * rs * g8[1] + be8[1];
            o0.z = (acc[i][2] - mu) * rs * g8[2] + be8[2];
            o0.w = (acc[i][3] - mu) * rs * g8[3] + be8[3];
            o1.x = (acc[i][4] - mu) * rs * g8[4] + be8[4];
            o1.y = (acc[i][5] - mu) * rs * g8[5] + be8[5];
            o1.z = (acc[i][6] - mu) * rs * g8[6] + be8[6];
            o1.w = (acc[i][7] - mu) * rs * g8[7] + be8[7];
            *reinterpret_cast<float4*>(out + (long)gr * OUT_C + cg * 8) = o0;
            *reinterpret_cast<float4*>(out + (long)gr * OUT_C + cg * 8 + 4) = o1;
        }
    }
}

extern "C" void kernel_launch(void* const* d_in, const int* in_sizes, int n_in,
                              void* d_out, int out_size, void* d_ws, size_t ws_size,
                              hipStream_t stream)
{
    const float* x       = (const float*)d_in[0];
    const int*   edge    = (const int*)d_in[1];
    const float* message = (const float*)d_in[2];
    const float* W1      = (const float*)d_in[3];
    const float* b1      = (const float*)d_in[4];
    const float* W2      = (const float*)d_in[5];
    const float* b2      = (const float*)d_in[6];
    const float* W3      = (const float*)d_in[7];
    const float* gamma   = (const float*)d_in[8];
    const float* beta    = (const float*)d_in[9];
    float* out  = (float*)d_out;
    float* aggr = (float*)d_ws;                 // [N_NODES, MSG_C] f32

    hipMemsetAsync(aggr, 0, (size_t)N_NODES * MSG_C * sizeof(float), stream);

    int sblocks = (N_EDGES * 16) / 256;         // 50000, exact
    scatter_add_kernel<<<sblocks, 256, 0, stream>>>(edge, message, aggr);

    int mblocks = (N_NODES + 63) / 64;          // 782
    mlp_ln_kernel<<<mblocks, 256, 0, stream>>>(x, aggr, W1, b1, W2, b2, W3,
                                               gamma, beta, out);
}

// Round 2
// 349.941 us; speedup vs baseline: 2.4098x; 2.4098x over previous
//
#include <hip/hip_runtime.h>

#define N_NODES 50000
#define N_EDGES 800000
#define IN_C 128
#define MSG_C 64
#define OUT_C 128

// ---------------------------------------------------------------------------
// CSR build: histogram -> exclusive scan -> fill edge list
// ---------------------------------------------------------------------------
__global__ __launch_bounds__(256) void hist_kernel(const int* __restrict__ edge_index,
                                                   int* __restrict__ deg)
{
    int e = blockIdx.x * 256 + threadIdx.x;
    if (e >= N_EDGES) return;
    atomicAdd(&deg[edge_index[N_EDGES + e]], 1);
}

__global__ __launch_bounds__(1024) void scan_kernel(const int* __restrict__ deg,
                                                    int* __restrict__ offsets)
{
    __shared__ int warpsum[16];
    __shared__ int s_carry;
    const int tid = threadIdx.x;
    const int lane = tid & 63;
    const int wid = tid >> 6;
    if (tid == 0) s_carry = 0;
    __syncthreads();
    for (int basei = 0; basei < N_NODES; basei += 1024) {
        int i = basei + tid;
        int v = (i < N_NODES) ? deg[i] : 0;
        int s = v;
        #pragma unroll
        for (int d = 1; d < 64; d <<= 1) {
            int t = __shfl_up(s, d);
            if (lane >= d) s += t;
        }
        if (lane == 63) warpsum[wid] = s;
        __syncthreads();
        if (wid == 0 && lane < 16) {
            int ws = warpsum[lane];
            int ss = ws;
            #pragma unroll
            for (int d = 1; d < 16; d <<= 1) {
                int t = __shfl_up(ss, d);
                if (lane >= d) ss += t;
            }
            warpsum[lane] = ss - ws;   // exclusive wave offset
        }
        __syncthreads();
        int carry = s_carry;
        if (i < N_NODES) offsets[i] = carry + s - v + warpsum[wid];
        __syncthreads();
        if (tid == 1023) s_carry = carry + s + warpsum[15];
        __syncthreads();
    }
    if (tid == 0) offsets[N_NODES] = s_carry;   // == N_EDGES
}

__global__ __launch_bounds__(256) void fill_kernel(const int* __restrict__ edge_index,
                                                   const int* __restrict__ offsets,
                                                   int* __restrict__ cursor,
                                                   int* __restrict__ elist)
{
    int e = blockIdx.x * 256 + threadIdx.x;
    if (e >= N_EDGES) return;
    int d = edge_index[N_EDGES + e];
    int pos = atomicAdd(&cursor[d], 1);
    elist[offsets[d] + pos] = e;
}

// ---------------------------------------------------------------------------
// gather: one wave per node, lane = channel; sums message rows (256B coalesced)
// block = 256 threads = 4 waves = 4 nodes
// ---------------------------------------------------------------------------
__global__ __launch_bounds__(256) void gather_kernel(const int* __restrict__ offsets,
                                                     const int* __restrict__ elist,
                                                     const float* __restrict__ message,
                                                     float* __restrict__ aggr)
{
    int wid = threadIdx.x >> 6;
    int lane = threadIdx.x & 63;
    int n = blockIdx.x * 4 + wid;
    if (n >= N_NODES) return;
    int start = offsets[n], end = offsets[n + 1];
    float acc = 0.f;
    int i = start;
    // 2-deep unroll so two message rows can be in flight
    for (; i + 2 <= end; i += 2) {
        int e0 = elist[i], e1 = elist[i + 1];
        float m0 = message[(long)e0 * MSG_C + lane];
        float m1 = message[(long)e1 * MSG_C + lane];
        acc += m0 + m1;
    }
    if (i < end) {
        int e0 = elist[i];
        acc += message[(long)e0 * MSG_C + lane];
    }
    aggr[(long)n * MSG_C + lane] = acc;
}

// ---------------- fused 3-layer MLP + LayerNorm (unchanged) -----------------
template<int STRIDE>
__device__ __forceinline__ void gemm_chunk(const float* __restrict__ A,
                                           const float* __restrict__ sWp,
                                           int rg, int cg, int kbase,
                                           float acc[4][8])
{
    #pragma unroll 4
    for (int kk = 0; kk < 64; ++kk) {
        float a[4];
        #pragma unroll
        for (int i = 0; i < 4; ++i)
            a[i] = A[(rg * 4 + i) * STRIDE + kbase + kk];   // broadcast reads
        float4 w0 = *reinterpret_cast<const float4*>(sWp + kk * 128 + cg * 8);
        float4 w1 = *reinterpret_cast<const float4*>(sWp + kk * 128 + cg * 8 + 4);
        float w[8] = {w0.x, w0.y, w0.z, w0.w, w1.x, w1.y, w1.z, w1.w};
        #pragma unroll
        for (int i = 0; i < 4; ++i)
            #pragma unroll
            for (int j = 0; j < 8; ++j)
                acc[i][j] += a[i] * w[j];
    }
}

__device__ __forceinline__ void load_w_chunk(const float* __restrict__ W, int krow0,
                                             float* __restrict__ sW, int tid)
{
    #pragma unroll
    for (int idx = tid; idx < 64 * 32; idx += 256) {
        int r = idx >> 5, c4 = idx & 31;
        *reinterpret_cast<float4*>(sW + r * 128 + c4 * 4) =
            *reinterpret_cast<const float4*>(W + (long)(krow0 + r) * 128 + c4 * 4);
    }
}

__global__ __launch_bounds__(256) void mlp_ln_kernel(
    const float* __restrict__ x, const float* __restrict__ aggr,
    const float* __restrict__ W1, const float* __restrict__ b1,
    const float* __restrict__ W2, const float* __restrict__ b2,
    const float* __restrict__ W3, const float* __restrict__ gamma,
    const float* __restrict__ beta, float* __restrict__ out)
{
    __shared__ float sA[64][196];   // h0 (192 cols), later reused for h2 (128)
    __shared__ float sB[64][132];   // h1
    __shared__ float sW[64][128];   // weight K-chunk

    const int tid = threadIdx.x;
    const int rg = tid >> 4;        // 0..15, 4 rows each
    const int cg = tid & 15;        // 0..15, 8 cols each
    const int base = blockIdx.x * 64;

    // ---- stage x -> sA[:,0:128]
    for (int idx = tid; idx < 64 * 32; idx += 256) {
        int r = idx >> 5, c4 = idx & 31;
        int gr = base + r;
        float4 v = make_float4(0.f, 0.f, 0.f, 0.f);
        if (gr < N_NODES) v = *reinterpret_cast<const float4*>(x + (long)gr * IN_C + c4 * 4);
        *reinterpret_cast<float4*>(&sA[r][c4 * 4]) = v;
    }
    // ---- stage aggr -> sA[:,128:192]
    for (int idx = tid; idx < 64 * 16; idx += 256) {
        int r = idx >> 4, c4 = idx & 15;
        int gr = base + r;
        float4 v = make_float4(0.f, 0.f, 0.f, 0.f);
        if (gr < N_NODES) v = *reinterpret_cast<const float4*>(aggr + (long)gr * MSG_C + c4 * 4);
        *reinterpret_cast<float4*>(&sA[r][IN_C + c4 * 4]) = v;
    }

    float acc[4][8];

    // ===== layer 1: h1 = leaky(h0 @ W1 + b1), K = 192
    #pragma unroll
    for (int i = 0; i < 4; ++i)
        #pragma unroll
        for (int j = 0; j < 8; ++j) acc[i][j] = 0.f;
    for (int kc = 0; kc < 3; ++kc) {
        __syncthreads();                       // sW free / sA staged
        load_w_chunk(W1, kc * 64, &sW[0][0], tid);
        __syncthreads();
        gemm_chunk<196>(&sA[0][0], &sW[0][0], rg, cg, kc * 64, acc);
    }
    #pragma unroll
    for (int i = 0; i < 4; ++i)
        #pragma unroll
        for (int j = 0; j < 8; ++j) {
            float v = acc[i][j] + b1[cg * 8 + j];
            v = v > 0.f ? v : 0.2f * v;
            sB[rg * 4 + i][cg * 8 + j] = v;
        }

    // ===== layer 2: h2 = leaky(h1 @ W2 + b2), K = 128
    #pragma unroll
    for (int i = 0; i < 4; ++i)
        #pragma unroll
        for (int j = 0; j < 8; ++j) acc[i][j] = 0.f;
    for (int kc = 0; kc < 2; ++kc) {
        __syncthreads();                       // also orders sB writes -> reads
        load_w_chunk(W2, kc * 64, &sW[0][0], tid);
        __syncthreads();
        gemm_chunk<132>(&sB[0][0], &sW[0][0], rg, cg, kc * 64, acc);
    }
    #pragma unroll
    for (int i = 0; i < 4; ++i)
        #pragma unroll
        for (int j = 0; j < 8; ++j) {
            float v = acc[i][j] + b2[cg * 8 + j];
            v = v > 0.f ? v : 0.2f * v;
            sA[rg * 4 + i][cg * 8 + j] = v;    // h2 reuses sA
        }

    // ===== layer 3: h3 = h2 @ W3 (no bias), K = 128
    #pragma unroll
    for (int i = 0; i < 4; ++i)
        #pragma unroll
        for (int j = 0; j < 8; ++j) acc[i][j] = 0.f;
    for (int kc = 0; kc < 2; ++kc) {
        __syncthreads();                       // orders h2 writes -> reads
        load_w_chunk(W3, kc * 64, &sW[0][0], tid);
        __syncthreads();
        gemm_chunk<196>(&sA[0][0], &sW[0][0], rg, cg, kc * 64, acc);
    }

    // ===== LayerNorm epilogue (row owned by 16 lanes: cg groups)
    float g8[8], be8[8];
    #pragma unroll
    for (int j = 0; j < 8; ++j) { g8[j] = gamma[cg * 8 + j]; be8[j] = beta[cg * 8 + j]; }

    #pragma unroll
    for (int i = 0; i < 4; ++i) {
        float s1 = 0.f, s2 = 0.f;
        #pragma unroll
        for (int j = 0; j < 8; ++j) { s1 += acc[i][j]; s2 += acc[i][j] * acc[i][j]; }
        #pragma unroll
        for (int m = 8; m >= 1; m >>= 1) {
            s1 += __shfl_xor(s1, m);
            s2 += __shfl_xor(s2, m);
        }
        float mu = s1 * (1.f / 128.f);
        float var = s2 * (1.f / 128.f) - mu * mu;
        float rs = rsqrtf(var + 1e-5f);
        int gr = base + rg * 4 + i;
        if (gr < N_NODES) {
            float4 o0, o1;
            o0.x = (acc[i][0] - mu) * rs * g8[0] + be8[0];
            o0.y = (acc[i][1] - mu) * rs * g8[1] + be8[1];
            o0.z = (acc[i][2] - mu) * rs * g8[2] + be8[2];
            o0.w = (acc[i][3] - mu) * rs * g8[3] + be8[3];
            o1.x = (acc[i][4] - mu) * rs * g8[4] + be8[4];
            o1.y = (acc[i][5] - mu) * rs * g8[5] + be8[5];
            o1.z = (acc[i][6] - mu) * rs * g8[6] + be8[6];
            o1.w = (acc[i][7] - mu) * rs * g8[7] + be8[7];
            *reinterpret_cast<float4*>(out + (long)gr * OUT_C + cg * 8) = o0;
            *reinterpret_cast<float4*>(out + (long)gr * OUT_C + cg * 8 + 4) = o1;
        }
    }
}

extern "C" void kernel_launch(void* const* d_in, const int* in_sizes, int n_in,
                              void* d_out, int out_size, void* d_ws, size_t ws_size,
                              hipStream_t stream)
{
    const float* x       = (const float*)d_in[0];
    const int*   edge    = (const int*)d_in[1];
    const float* message = (const float*)d_in[2];
    const float* W1      = (const float*)d_in[3];
    const float* b1      = (const float*)d_in[4];
    const float* W2      = (const float*)d_in[5];
    const float* b2      = (const float*)d_in[6];
    const float* W3      = (const float*)d_in[7];
    const float* gamma   = (const float*)d_in[8];
    const float* beta    = (const float*)d_in[9];
    float* out  = (float*)d_out;

    // ---- workspace layout (16.6 MB) ----
    char* ws = (char*)d_ws;
    float* aggr    = (float*)(ws);                         // 12,800,000 B
    int*   deg     = (int*)  (ws + 12800000);              //    200,000 B
    int*   offsets = (int*)  (ws + 13000000);              //    200,016 B (N+1)
    int*   cursor  = (int*)  (ws + 13200016);              //    200,000 B
    int*   elist   = (int*)  (ws + 13400016);              //  3,200,000 B

    // zero deg + offsets + cursor in one shot (offsets overwritten anyway)
    hipMemsetAsync(deg, 0, 600016, stream);

    int eblocks = (N_EDGES + 255) / 256;
    hist_kernel<<<eblocks, 256, 0, stream>>>(edge, deg);
    scan_kernel<<<1, 1024, 0, stream>>>(deg, offsets);
    fill_kernel<<<eblocks, 256, 0, stream>>>(edge, offsets, cursor, elist);

    int gblocks = (N_NODES + 3) / 4;
    gather_kernel<<<gblocks, 256, 0, stream>>>(offsets, elist, message, aggr);

    int mblocks = (N_NODES + 63) / 64;          // 782
    mlp_ln_kernel<<<mblocks, 256, 0, stream>>>(x, aggr, W1, b1, W2, b2, W3,
                                               gamma, beta, out);
}

// Round 3
// 218.301 us; speedup vs baseline: 3.8630x; 1.6030x over previous
//
#include <hip/hip_runtime.h>

#define N_NODES 50000
#define N_EDGES 800000
#define IN_C 128
#define MSG_C 64
#define OUT_C 128
#define SCAN_NB 49   // ceil(50000/1024)

typedef __attribute__((ext_vector_type(8))) short short8v;  // 8 bf16 (4 VGPRs)
typedef __attribute__((ext_vector_type(4))) float f32x4;

__device__ __forceinline__ unsigned short f2bf(float f) {
    union { float f; unsigned int u; } v; v.f = f;
    unsigned int r = (v.u + 0x7FFFu + ((v.u >> 16) & 1u)) >> 16;
    return (unsigned short)r;
}

// ---------------------------------------------------------------------------
// CSR build: histogram -> two-level scan -> fill edge list
// ---------------------------------------------------------------------------
__global__ __launch_bounds__(256) void hist_kernel(const int* __restrict__ edge_index,
                                                   int* __restrict__ deg)
{
    int e = blockIdx.x * 256 + threadIdx.x;
    if (e >= N_EDGES) return;
    atomicAdd(&deg[edge_index[N_EDGES + e]], 1);
}

__global__ __launch_bounds__(1024) void scan_a_kernel(const int* __restrict__ deg,
                                                      int* __restrict__ offsets,
                                                      int* __restrict__ bsum)
{
    __shared__ int wsum[16];
    const int tid = threadIdx.x, lane = tid & 63, wid = tid >> 6;
    int i = blockIdx.x * 1024 + tid;
    int v = (i < N_NODES) ? deg[i] : 0;
    int s = v;
    #pragma unroll
    for (int d = 1; d < 64; d <<= 1) {
        int t = __shfl_up(s, d);
        if (lane >= d) s += t;
    }
    if (lane == 63) wsum[wid] = s;
    __syncthreads();
    if (wid == 0 && lane < 16) {
        int ws = wsum[lane];
        int ss = ws;
        #pragma unroll
        for (int d = 1; d < 16; d <<= 1) {
            int t = __shfl_up(ss, d);
            if (lane >= d) ss += t;
        }
        wsum[lane] = ss - ws;   // exclusive wave offset
    }
    __syncthreads();
    if (i < N_NODES) offsets[i] = s - v + wsum[wid];
    if (tid == 1023) bsum[blockIdx.x] = wsum[15] + s;
}

__global__ __launch_bounds__(64) void scan_b_kernel(int* __restrict__ bsum,
                                                    int* __restrict__ offsets)
{
    int lane = threadIdx.x;
    int v = (lane < SCAN_NB) ? bsum[lane] : 0;
    int s = v;
    #pragma unroll
    for (int d = 1; d < 64; d <<= 1) {
        int t = __shfl_up(s, d);
        if (lane >= d) s += t;
    }
    if (lane < SCAN_NB) bsum[lane] = s - v;      // exclusive block offset
    if (lane == 63) offsets[N_NODES] = s;        // grand total == N_EDGES
}

__global__ __launch_bounds__(256) void scan_c_kernel(int* __restrict__ offsets,
                                                     const int* __restrict__ bsum)
{
    int i = blockIdx.x * 256 + threadIdx.x;
    if (i < N_NODES) offsets[i] += bsum[i >> 10];
}

__global__ __launch_bounds__(256) void fill_kernel(const int* __restrict__ edge_index,
                                                   const int* __restrict__ offsets,
                                                   int* __restrict__ cursor,
                                                   int* __restrict__ elist)
{
    int e = blockIdx.x * 256 + threadIdx.x;
    if (e >= N_EDGES) return;
    int d = edge_index[N_EDGES + e];
    int pos = atomicAdd(&cursor[d], 1);
    elist[offsets[d] + pos] = e;
}

// ---------------------------------------------------------------------------
// gather: one wave per node, lane = channel; outputs bf16 aggr
// ---------------------------------------------------------------------------
__global__ __launch_bounds__(256) void gather_kernel(const int* __restrict__ offsets,
                                                     const int* __restrict__ elist,
                                                     const float* __restrict__ message,
                                                     unsigned short* __restrict__ aggr_bf)
{
    int wid = threadIdx.x >> 6;
    int lane = threadIdx.x & 63;
    int n = blockIdx.x * 4 + wid;
    if (n >= N_NODES) return;
    int start = offsets[n], end = offsets[n + 1];
    float acc = 0.f;
    int i = start;
    for (; i + 2 <= end; i += 2) {
        int e0 = elist[i], e1 = elist[i + 1];
        float m0 = message[(long)e0 * MSG_C + lane];
        float m1 = message[(long)e1 * MSG_C + lane];
        acc += m0 + m1;
    }
    if (i < end) acc += message[(long)elist[i] * MSG_C + lane];
    aggr_bf[(long)n * MSG_C + lane] = f2bf(acc);
}

// ---------------------------------------------------------------------------
// weight transpose + bf16 convert: Wt[n][k] = bf16(W[k][n])
// ---------------------------------------------------------------------------
__global__ __launch_bounds__(256) void convert_w_kernel(
    const float* __restrict__ W1, const float* __restrict__ W2,
    const float* __restrict__ W3, unsigned short* __restrict__ Wt1,
    unsigned short* __restrict__ Wt2, unsigned short* __restrict__ Wt3)
{
    int idx = blockIdx.x * 256 + threadIdx.x;
    if (idx < 24576) {
        int k = idx >> 7, n = idx & 127;
        Wt1[n * 192 + k] = f2bf(W1[idx]);
    } else if (idx < 40960) {
        int t = idx - 24576;
        int k = t >> 7, n = t & 127;
        Wt2[n * 128 + k] = f2bf(W2[t]);
    } else if (idx < 57344) {
        int t = idx - 40960;
        int k = t >> 7, n = t & 127;
        Wt3[n * 128 + k] = f2bf(W3[t]);
    }
}

// ---------------------------------------------------------------------------
// MFMA MLP + LayerNorm. 256 thr = 4 waves; wave owns 16 rows x 128 cols.
// Wave-private LDS slices -> NO __syncthreads anywhere.
// A-frag: row = lane&15, k = (lane>>4)*8 + j (ds_read_b128 from padded LDS)
// B-frag: col = lane&15, k = (lane>>4)*8 + j (global 16B from Wt[n][k], cached)
// C/D  : col = lane&15, row = (lane>>4)*4 + j   [m89-verified]
// ---------------------------------------------------------------------------
template<int KW, int AS, bool BIAS>
__device__ __forceinline__ void layer_mfma(const unsigned short* __restrict__ A,
                                           const unsigned short* __restrict__ Wt,
                                           const float* __restrict__ bias,
                                           int lr, int lg, f32x4 acc[8])
{
    #pragma unroll
    for (int ct = 0; ct < 8; ++ct) {
        float bv = BIAS ? bias[ct * 16 + lr] : 0.f;
        acc[ct] = (f32x4){bv, bv, bv, bv};
    }
    #pragma unroll
    for (int ks = 0; ks < KW / 32; ++ks) {
        short8v a = *reinterpret_cast<const short8v*>(A + lr * AS + ks * 32 + lg * 8);
        #pragma unroll
        for (int ct = 0; ct < 8; ++ct) {
            short8v b = *reinterpret_cast<const short8v*>(
                Wt + (size_t)(ct * 16 + lr) * KW + ks * 32 + lg * 8);
            acc[ct] = __builtin_amdgcn_mfma_f32_16x16x32_bf16(a, b, acc[ct], 0, 0, 0);
        }
    }
}

__device__ __forceinline__ void store_h_leaky(unsigned short* __restrict__ H,
                                              int lr, int lg, const f32x4 acc[8])
{
    #pragma unroll
    for (int ct = 0; ct < 8; ++ct)
        #pragma unroll
        for (int j = 0; j < 4; ++j) {
            float v = acc[ct][j];
            v = v > 0.f ? v : 0.2f * v;
            H[(lg * 4 + j) * 136 + ct * 16 + lr] = f2bf(v);
        }
}

__global__ __launch_bounds__(256, 2) void mlp_mfma_kernel(
    const float* __restrict__ x, const unsigned short* __restrict__ aggr_bf,
    const unsigned short* __restrict__ Wt1, const float* __restrict__ b1,
    const unsigned short* __restrict__ Wt2, const float* __restrict__ b2,
    const unsigned short* __restrict__ Wt3, const float* __restrict__ gamma,
    const float* __restrict__ beta, float* __restrict__ out)
{
    __shared__ __align__(16) unsigned short sA0[4][16][200];     // h0, stride 400B
    __shared__ __align__(16) unsigned short sH[4][2][16][136];   // h1,h2 stride 272B

    const int tid = threadIdx.x;
    const int w = tid >> 6, l = tid & 63;
    const int lr = l & 15, lg = l >> 4;
    const int R0 = blockIdx.x * 64 + w * 16;
    if (R0 >= N_NODES) return;    // N % 16 == 0: waves are all-or-nothing

    // ---- stage x (f32 -> bf16) into sA0[:, 0:128]
    #pragma unroll
    for (int i = 0; i < 4; ++i) {
        int r = lg + i * 4;
        int c0 = lr * 8;
        const float4* xp = reinterpret_cast<const float4*>(x + (size_t)(R0 + r) * IN_C + c0);
        float4 v0 = xp[0], v1 = xp[1];
        uint4 p;
        p.x = (unsigned)f2bf(v0.x) | ((unsigned)f2bf(v0.y) << 16);
        p.y = (unsigned)f2bf(v0.z) | ((unsigned)f2bf(v0.w) << 16);
        p.z = (unsigned)f2bf(v1.x) | ((unsigned)f2bf(v1.y) << 16);
        p.w = (unsigned)f2bf(v1.z) | ((unsigned)f2bf(v1.w) << 16);
        *reinterpret_cast<uint4*>(&sA0[w][r][c0]) = p;
    }
    // ---- stage aggr (already bf16) into sA0[:, 128:192]
    #pragma unroll
    for (int i = 0; i < 2; ++i) {
        int r = (l >> 3) + i * 8;
        int c0 = (l & 7) * 8;
        uint4 a4 = *reinterpret_cast<const uint4*>(aggr_bf + (size_t)(R0 + r) * MSG_C + c0);
        *reinterpret_cast<uint4*>(&sA0[w][r][IN_C + c0]) = a4;
    }

    f32x4 acc[8];

    // layer 1: K=192
    layer_mfma<192, 200, true>(&sA0[w][0][0], Wt1, b1, lr, lg, acc);
    store_h_leaky(&sH[w][0][0][0], lr, lg, acc);

    // layer 2: K=128
    layer_mfma<128, 136, true>(&sH[w][0][0][0], Wt2, b2, lr, lg, acc);
    store_h_leaky(&sH[w][1][0][0], lr, lg, acc);

    // layer 3: K=128, no bias
    layer_mfma<128, 136, false>(&sH[w][1][0][0], Wt3, nullptr, lr, lg, acc);

    // ---- LayerNorm epilogue (row r held by the 16 lanes of group lg, per j)
    float g8[8], be8[8];
    #pragma unroll
    for (int ct = 0; ct < 8; ++ct) {
        g8[ct] = gamma[ct * 16 + lr];
        be8[ct] = beta[ct * 16 + lr];
    }
    #pragma unroll
    for (int j = 0; j < 4; ++j) {
        float s1 = 0.f, s2 = 0.f;
        #pragma unroll
        for (int ct = 0; ct < 8; ++ct) {
            float v = acc[ct][j];
            s1 += v; s2 += v * v;
        }
        #pragma unroll
        for (int m = 8; m >= 1; m >>= 1) {
            s1 += __shfl_xor(s1, m);
            s2 += __shfl_xor(s2, m);
        }
        float mu = s1 * (1.f / 128.f);
        float var = s2 * (1.f / 128.f) - mu * mu;
        float rs = rsqrtf(var + 1e-5f);
        int gr = R0 + lg * 4 + j;
        #pragma unroll
        for (int ct = 0; ct < 8; ++ct)
            out[(size_t)gr * OUT_C + ct * 16 + lr] =
                (acc[ct][j] - mu) * rs * g8[ct] + be8[ct];
    }
}

extern "C" void kernel_launch(void* const* d_in, const int* in_sizes, int n_in,
                              void* d_out, int out_size, void* d_ws, size_t ws_size,
                              hipStream_t stream)
{
    const float* x       = (const float*)d_in[0];
    const int*   edge    = (const int*)d_in[1];
    const float* message = (const float*)d_in[2];
    const float* W1      = (const float*)d_in[3];
    const float* b1      = (const float*)d_in[4];
    const float* W2      = (const float*)d_in[5];
    const float* b2      = (const float*)d_in[6];
    const float* W3      = (const float*)d_in[7];
    const float* gamma   = (const float*)d_in[8];
    const float* beta    = (const float*)d_in[9];
    float* out  = (float*)d_out;

    // ---- workspace layout (~10.3 MB) ----
    char* ws = (char*)d_ws;
    unsigned short* aggr_bf = (unsigned short*)(ws);        //  6,400,000 B
    int*   deg     = (int*)(ws + 6400000);                  //    200,000 B
    int*   offsets = (int*)(ws + 6600000);                  //    200,016 B (N+1)
    int*   cursor  = (int*)(ws + 6800016);                  //    200,000 B
    int*   elist   = (int*)(ws + 7000016);                  //  3,200,000 B
    unsigned short* Wt1 = (unsigned short*)(ws + 10200016); //     49,152 B
    unsigned short* Wt2 = (unsigned short*)(ws + 10249168); //     32,768 B
    unsigned short* Wt3 = (unsigned short*)(ws + 10281936); //     32,768 B
    int*   bsum    = (int*)(ws + 10314704);                 //        196 B

    convert_w_kernel<<<224, 256, 0, stream>>>(W1, W2, W3, Wt1, Wt2, Wt3);
    hipMemsetAsync(deg, 0, 600016, stream);   // deg + offsets + cursor

    int eblocks = (N_EDGES + 255) / 256;
    hist_kernel<<<eblocks, 256, 0, stream>>>(edge, deg);
    scan_a_kernel<<<SCAN_NB, 1024, 0, stream>>>(deg, offsets, bsum);
    scan_b_kernel<<<1, 64, 0, stream>>>(bsum, offsets);
    scan_c_kernel<<<(N_NODES + 255) / 256, 256, 0, stream>>>(offsets, bsum);
    fill_kernel<<<eblocks, 256, 0, stream>>>(edge, offsets, cursor, elist);

    gather_kernel<<<(N_NODES + 3) / 4, 256, 0, stream>>>(offsets, elist, message, aggr_bf);

    mlp_mfma_kernel<<<(N_NODES + 63) / 64, 256, 0, stream>>>(
        x, aggr_bf, Wt1, b1, Wt2, b2, Wt3, gamma, beta, out);
}

// Round 4
// 217.662 us; speedup vs baseline: 3.8744x; 1.0029x over previous
//
#include <hip/hip_runtime.h>

#define N_NODES 50000
#define N_EDGES 800000
#define IN_C 128
#define MSG_C 64
#define OUT_C 128
#define SCAN_NB 49   // ceil(50000/1024)

typedef __attribute__((ext_vector_type(8))) short short8v;  // 8 bf16 (4 VGPRs)
typedef __attribute__((ext_vector_type(4))) float f32x4;

__device__ __forceinline__ unsigned short f2bf(float f) {
    union { float f; unsigned int u; } v; v.f = f;
    unsigned int r = (v.u + 0x7FFFu + ((v.u >> 16) & 1u)) >> 16;
    return (unsigned short)r;
}

// ---------------------------------------------------------------------------
// zero deg+cursor (contiguous 400,000 B) — replaces pathologically slow
// rocclr fillBuffer (116 us for 600 KB measured in round 3)
// ---------------------------------------------------------------------------
__global__ __launch_bounds__(256) void zero_kernel(int4* __restrict__ p, int n4)
{
    int i = blockIdx.x * 256 + threadIdx.x;
    if (i < n4) p[i] = make_int4(0, 0, 0, 0);
}

// ---------------------------------------------------------------------------
// CSR build: histogram -> two-level scan -> fill edge list
// ---------------------------------------------------------------------------
__global__ __launch_bounds__(256) void hist_kernel(const int* __restrict__ edge_index,
                                                   int* __restrict__ deg)
{
    int e = blockIdx.x * 256 + threadIdx.x;
    if (e >= N_EDGES) return;
    atomicAdd(&deg[edge_index[N_EDGES + e]], 1);
}

__global__ __launch_bounds__(1024) void scan_a_kernel(const int* __restrict__ deg,
                                                      int* __restrict__ offsets,
                                                      int* __restrict__ bsum)
{
    __shared__ int wsum[16];
    const int tid = threadIdx.x, lane = tid & 63, wid = tid >> 6;
    int i = blockIdx.x * 1024 + tid;
    int v = (i < N_NODES) ? deg[i] : 0;
    int s = v;
    #pragma unroll
    for (int d = 1; d < 64; d <<= 1) {
        int t = __shfl_up(s, d);
        if (lane >= d) s += t;
    }
    if (lane == 63) wsum[wid] = s;
    __syncthreads();
    if (wid == 0 && lane < 16) {
        int ws = wsum[lane];
        int ss = ws;
        #pragma unroll
        for (int d = 1; d < 16; d <<= 1) {
            int t = __shfl_up(ss, d);
            if (lane >= d) ss += t;
        }
        wsum[lane] = ss - ws;   // exclusive wave offset
    }
    __syncthreads();
    if (i < N_NODES) offsets[i] = s - v + wsum[wid];
    if (tid == 1023) bsum[blockIdx.x] = wsum[15] + s;
}

__global__ __launch_bounds__(64) void scan_b_kernel(int* __restrict__ bsum,
                                                    int* __restrict__ offsets)
{
    int lane = threadIdx.x;
    int v = (lane < SCAN_NB) ? bsum[lane] : 0;
    int s = v;
    #pragma unroll
    for (int d = 1; d < 64; d <<= 1) {
        int t = __shfl_up(s, d);
        if (lane >= d) s += t;
    }
    if (lane < SCAN_NB) bsum[lane] = s - v;      // exclusive block offset
    if (lane == 63) offsets[N_NODES] = s;        // grand total == N_EDGES
}

__global__ __launch_bounds__(256) void scan_c_kernel(int* __restrict__ offsets,
                                                     const int* __restrict__ bsum)
{
    int i = blockIdx.x * 256 + threadIdx.x;
    if (i < N_NODES) offsets[i] += bsum[i >> 10];
}

__global__ __launch_bounds__(256) void fill_kernel(const int* __restrict__ edge_index,
                                                   const int* __restrict__ offsets,
                                                   int* __restrict__ cursor,
                                                   int* __restrict__ elist)
{
    int e = blockIdx.x * 256 + threadIdx.x;
    if (e >= N_EDGES) return;
    int d = edge_index[N_EDGES + e];
    int pos = atomicAdd(&cursor[d], 1);
    elist[offsets[d] + pos] = e;
}

// ---------------------------------------------------------------------------
// gather: one wave per node, lane = channel; outputs bf16 aggr
// ---------------------------------------------------------------------------
__global__ __launch_bounds__(256) void gather_kernel(const int* __restrict__ offsets,
                                                     const int* __restrict__ elist,
                                                     const float* __restrict__ message,
                                                     unsigned short* __restrict__ aggr_bf)
{
    int wid = threadIdx.x >> 6;
    int lane = threadIdx.x & 63;
    int n = blockIdx.x * 4 + wid;
    if (n >= N_NODES) return;
    int start = offsets[n], end = offsets[n + 1];
    float acc = 0.f;
    int i = start;
    for (; i + 2 <= end; i += 2) {
        int e0 = elist[i], e1 = elist[i + 1];
        float m0 = message[(long)e0 * MSG_C + lane];
        float m1 = message[(long)e1 * MSG_C + lane];
        acc += m0 + m1;
    }
    if (i < end) acc += message[(long)elist[i] * MSG_C + lane];
    aggr_bf[(long)n * MSG_C + lane] = f2bf(acc);
}

// ---------------------------------------------------------------------------
// weight transpose + bf16 convert: Wt[n][k] = bf16(W[k][n])
// ---------------------------------------------------------------------------
__global__ __launch_bounds__(256) void convert_w_kernel(
    const float* __restrict__ W1, const float* __restrict__ W2,
    const float* __restrict__ W3, unsigned short* __restrict__ Wt1,
    unsigned short* __restrict__ Wt2, unsigned short* __restrict__ Wt3)
{
    int idx = blockIdx.x * 256 + threadIdx.x;
    if (idx < 24576) {
        int k = idx >> 7, n = idx & 127;
        Wt1[n * 192 + k] = f2bf(W1[idx]);
    } else if (idx < 40960) {
        int t = idx - 24576;
        int k = t >> 7, n = t & 127;
        Wt2[n * 128 + k] = f2bf(W2[t]);
    } else if (idx < 57344) {
        int t = idx - 40960;
        int k = t >> 7, n = t & 127;
        Wt3[n * 128 + k] = f2bf(W3[t]);
    }
}

// ---------------------------------------------------------------------------
// MFMA MLP + LayerNorm. 256 thr = 4 waves; wave owns 16 rows x 128 cols.
// Wave-private LDS slices -> NO __syncthreads anywhere.
// A-frag: row = lane&15, k = (lane>>4)*8 + j (ds_read_b128 from padded LDS)
// B-frag: col = lane&15, k = (lane>>4)*8 + j (global 16B from Wt[n][k], cached)
// C/D  : col = lane&15, row = (lane>>4)*4 + j   [m89-verified]
// ---------------------------------------------------------------------------
template<int KW, int AS, bool BIAS>
__device__ __forceinline__ void layer_mfma(const unsigned short* __restrict__ A,
                                           const unsigned short* __restrict__ Wt,
                                           const float* __restrict__ bias,
                                           int lr, int lg, f32x4 acc[8])
{
    #pragma unroll
    for (int ct = 0; ct < 8; ++ct) {
        float bv = BIAS ? bias[ct * 16 + lr] : 0.f;
        acc[ct] = (f32x4){bv, bv, bv, bv};
    }
    #pragma unroll
    for (int ks = 0; ks < KW / 32; ++ks) {
        short8v a = *reinterpret_cast<const short8v*>(A + lr * AS + ks * 32 + lg * 8);
        #pragma unroll
        for (int ct = 0; ct < 8; ++ct) {
            short8v b = *reinterpret_cast<const short8v*>(
                Wt + (size_t)(ct * 16 + lr) * KW + ks * 32 + lg * 8);
            acc[ct] = __builtin_amdgcn_mfma_f32_16x16x32_bf16(a, b, acc[ct], 0, 0, 0);
        }
    }
}

__device__ __forceinline__ void store_h_leaky(unsigned short* __restrict__ H,
                                              int lr, int lg, const f32x4 acc[8])
{
    #pragma unroll
    for (int ct = 0; ct < 8; ++ct)
        #pragma unroll
        for (int j = 0; j < 4; ++j) {
            float v = acc[ct][j];
            v = v > 0.f ? v : 0.2f * v;
            H[(lg * 4 + j) * 136 + ct * 16 + lr] = f2bf(v);
        }
}

__global__ __launch_bounds__(256, 2) void mlp_mfma_kernel(
    const float* __restrict__ x, const unsigned short* __restrict__ aggr_bf,
    const unsigned short* __restrict__ Wt1, const float* __restrict__ b1,
    const unsigned short* __restrict__ Wt2, const float* __restrict__ b2,
    const unsigned short* __restrict__ Wt3, const float* __restrict__ gamma,
    const float* __restrict__ beta, float* __restrict__ out)
{
    __shared__ __align__(16) unsigned short sA0[4][16][200];     // h0, stride 400B
    __shared__ __align__(16) unsigned short sH[4][2][16][136];   // h1,h2 stride 272B

    const int tid = threadIdx.x;
    const int w = tid >> 6, l = tid & 63;
    const int lr = l & 15, lg = l >> 4;
    const int R0 = blockIdx.x * 64 + w * 16;
    if (R0 >= N_NODES) return;    // N % 16 == 0: waves are all-or-nothing

    // ---- stage x (f32 -> bf16) into sA0[:, 0:128]
    #pragma unroll
    for (int i = 0; i < 4; ++i) {
        int r = lg + i * 4;
        int c0 = lr * 8;
        const float4* xp = reinterpret_cast<const float4*>(x + (size_t)(R0 + r) * IN_C + c0);
        float4 v0 = xp[0], v1 = xp[1];
        uint4 p;
        p.x = (unsigned)f2bf(v0.x) | ((unsigned)f2bf(v0.y) << 16);
        p.y = (unsigned)f2bf(v0.z) | ((unsigned)f2bf(v0.w) << 16);
        p.z = (unsigned)f2bf(v1.x) | ((unsigned)f2bf(v1.y) << 16);
        p.w = (unsigned)f2bf(v1.z) | ((unsigned)f2bf(v1.w) << 16);
        *reinterpret_cast<uint4*>(&sA0[w][r][c0]) = p;
    }
    // ---- stage aggr (already bf16) into sA0[:, 128:192]
    #pragma unroll
    for (int i = 0; i < 2; ++i) {
        int r = (l >> 3) + i * 8;
        int c0 = (l & 7) * 8;
        uint4 a4 = *reinterpret_cast<const uint4*>(aggr_bf + (size_t)(R0 + r) * MSG_C + c0);
        *reinterpret_cast<uint4*>(&sA0[w][r][IN_C + c0]) = a4;
    }

    f32x4 acc[8];

    // layer 1: K=192
    layer_mfma<192, 200, true>(&sA0[w][0][0], Wt1, b1, lr, lg, acc);
    store_h_leaky(&sH[w][0][0][0], lr, lg, acc);

    // layer 2: K=128
    layer_mfma<128, 136, true>(&sH[w][0][0][0], Wt2, b2, lr, lg, acc);
    store_h_leaky(&sH[w][1][0][0], lr, lg, acc);

    // layer 3: K=128, no bias
    layer_mfma<128, 136, false>(&sH[w][1][0][0], Wt3, nullptr, lr, lg, acc);

    // ---- LayerNorm epilogue (row r held by the 16 lanes of group lg, per j)
    float g8[8], be8[8];
    #pragma unroll
    for (int ct = 0; ct < 8; ++ct) {
        g8[ct] = gamma[ct * 16 + lr];
        be8[ct] = beta[ct * 16 + lr];
    }
    #pragma unroll
    for (int j = 0; j < 4; ++j) {
        float s1 = 0.f, s2 = 0.f;
        #pragma unroll
        for (int ct = 0; ct < 8; ++ct) {
            float v = acc[ct][j];
            s1 += v; s2 += v * v;
        }
        #pragma unroll
        for (int m = 8; m >= 1; m >>= 1) {
            s1 += __shfl_xor(s1, m);
            s2 += __shfl_xor(s2, m);
        }
        float mu = s1 * (1.f / 128.f);
        float var = s2 * (1.f / 128.f) - mu * mu;
        float rs = rsqrtf(var + 1e-5f);
        int gr = R0 + lg * 4 + j;
        #pragma unroll
        for (int ct = 0; ct < 8; ++ct)
            out[(size_t)gr * OUT_C + ct * 16 + lr] =
                (acc[ct][j] - mu) * rs * g8[ct] + be8[ct];
    }
}

extern "C" void kernel_launch(void* const* d_in, const int* in_sizes, int n_in,
                              void* d_out, int out_size, void* d_ws, size_t ws_size,
                              hipStream_t stream)
{
    const float* x       = (const float*)d_in[0];
    const int*   edge    = (const int*)d_in[1];
    const float* message = (const float*)d_in[2];
    const float* W1      = (const float*)d_in[3];
    const float* b1      = (const float*)d_in[4];
    const float* W2      = (const float*)d_in[5];
    const float* b2      = (const float*)d_in[6];
    const float* W3      = (const float*)d_in[7];
    const float* gamma   = (const float*)d_in[8];
    const float* beta    = (const float*)d_in[9];
    float* out  = (float*)d_out;

    // ---- workspace layout (~10.3 MB) ----
    // deg and cursor adjacent -> single contiguous 400,000 B zero
    char* ws = (char*)d_ws;
    unsigned short* aggr_bf = (unsigned short*)(ws);        //  6,400,000 B
    int*   deg     = (int*)(ws + 6400000);                  //    200,000 B
    int*   cursor  = (int*)(ws + 6600000);                  //    200,000 B
    int*   offsets = (int*)(ws + 6800000);                  //    200,016 B (N+1)
    int*   elist   = (int*)(ws + 7000016);                  //  3,200,000 B
    unsigned short* Wt1 = (unsigned short*)(ws + 10200016); //     49,152 B
    unsigned short* Wt2 = (unsigned short*)(ws + 10249168); //     32,768 B
    unsigned short* Wt3 = (unsigned short*)(ws + 10281936); //     32,768 B
    int*   bsum    = (int*)(ws + 10314704);                 //        196 B

    convert_w_kernel<<<224, 256, 0, stream>>>(W1, W2, W3, Wt1, Wt2, Wt3);

    // zero deg+cursor: 400,000 B = 25,000 int4
    zero_kernel<<<(25000 + 255) / 256, 256, 0, stream>>>((int4*)deg, 25000);

    int eblocks = (N_EDGES + 255) / 256;
    hist_kernel<<<eblocks, 256, 0, stream>>>(edge, deg);
    scan_a_kernel<<<SCAN_NB, 1024, 0, stream>>>(deg, offsets, bsum);
    scan_b_kernel<<<1, 64, 0, stream>>>(bsum, offsets);
    scan_c_kernel<<<(N_NODES + 255) / 256, 256, 0, stream>>>(offsets, bsum);
    fill_kernel<<<eblocks, 256, 0, stream>>>(edge, offsets, cursor, elist);

    gather_kernel<<<(N_NODES + 3) / 4, 256, 0, stream>>>(offsets, elist, message, aggr_bf);

    mlp_mfma_kernel<<<(N_NODES + 63) / 64, 256, 0, stream>>>(
        x, aggr_bf, Wt1, b1, Wt2, b2, Wt3, gamma, beta, out);
}